// Round 3
// baseline (374.515 us; speedup 1.0000x reference)
//
#include <hip/hip_runtime.h>
#include <hip/hip_bf16.h>
#include <math.h>

#define S_LEN 2048
#define BATCH 2
#define HID 1024
#define NHEAD 16
#define HDIM 64
#define NTOK (S_LEN*BATCH)   // 4096

typedef __bf16 bf16;
typedef __bf16 bf16x4 __attribute__((ext_vector_type(4)));
typedef __bf16 bf16x8 __attribute__((ext_vector_type(8)));
typedef float f32x4 __attribute__((ext_vector_type(4)));

typedef const __attribute__((address_space(1))) unsigned int* gptr_t;
typedef __attribute__((address_space(3))) unsigned int* lptr_t;

__device__ __forceinline__ void gload16(const void* g, void* l) {
    __builtin_amdgcn_global_load_lds((gptr_t)g, (lptr_t)l, 16, 0, 0);
}

// ---------------- fp32 -> bf16 convert (8 elems/thread) ----------------
__global__ void cvt_f32_bf16(const float* __restrict__ src, bf16* __restrict__ dst, int n) {
    int i = (blockIdx.x * blockDim.x + threadIdx.x) * 8;
    if (i >= n) return;
    const float4* s = (const float4*)(src + i);
    float4 a = s[0], b = s[1];
    bf16x8 o;
    o[0] = (bf16)a.x; o[1] = (bf16)a.y; o[2] = (bf16)a.z; o[3] = (bf16)a.w;
    o[4] = (bf16)b.x; o[5] = (bf16)b.y; o[6] = (bf16)b.z; o[7] = (bf16)b.w;
    *(bf16x8*)(dst + i) = o;
}

// ---------------- GEMM: C[M][N] = A[M][K] * B[N][K]^T ----------------
// mode 0: QKV epilogue (N=3072): q/k -> head layout [32][2048][64]; v -> vT [32][64][2048]
// mode 1: OUT epilogue (N=1024): fp32 token-major + bias
#define BM 128
#define BN 128
#define BK 32

__global__ __launch_bounds__(256) void gemm_bt(
    const bf16* __restrict__ A, const bf16* __restrict__ B,
    int M, int N, int K, int mode,
    const float* __restrict__ bq, const float* __restrict__ bk,
    const float* __restrict__ bv, const float* __restrict__ bo,
    bf16* __restrict__ qh, bf16* __restrict__ kh, bf16* __restrict__ vT,
    float* __restrict__ outp)
{
    __shared__ __align__(16) bf16 As[BM * BK];
    __shared__ __align__(16) bf16 Bs[BN * BK];
    const int tid = threadIdx.x;
    const int lane = tid & 63, wv = tid >> 6;
    const int g = lane >> 4, l15 = lane & 15;
    const int wr = wv >> 1, wc = wv & 1;
    const int bm = blockIdx.y * BM, bn = blockIdx.x * BN;

    f32x4 zero4 = {0.f, 0.f, 0.f, 0.f};
    f32x4 acc[4][4];
#pragma unroll
    for (int mi = 0; mi < 4; mi++)
#pragma unroll
        for (int ni = 0; ni < 4; ni++) acc[mi][ni] = zero4;

    const int r0 = wv * 32 + (lane >> 2);
    const int c0 = (lane & 3) * 8;
    const bf16* Ag0 = A + (size_t)(bm + r0) * K + c0;
    const bf16* Ag1 = Ag0 + (size_t)16 * K;
    const bf16* Bg0 = B + (size_t)(bn + r0) * K + c0;
    const bf16* Bg1 = Bg0 + (size_t)16 * K;
    bf16* AsW = &As[(wv * 32) * BK];
    bf16* BsW = &Bs[(wv * 32) * BK];

    for (int k0 = 0; k0 < K; k0 += BK) {
        gload16(Ag0 + k0, AsW);
        gload16(Ag1 + k0, AsW + 16 * BK);
        gload16(Bg0 + k0, BsW);
        gload16(Bg1 + k0, BsW + 16 * BK);
        __syncthreads();

        bf16x8 aF[4], bF[4];
#pragma unroll
        for (int mi = 0; mi < 4; mi++)
            aF[mi] = *(const bf16x8*)&As[(wr * 64 + mi * 16 + l15) * BK + g * 8];
#pragma unroll
        for (int ni = 0; ni < 4; ni++)
            bF[ni] = *(const bf16x8*)&Bs[(wc * 64 + ni * 16 + l15) * BK + g * 8];
#pragma unroll
        for (int mi = 0; mi < 4; mi++)
#pragma unroll
            for (int ni = 0; ni < 4; ni++)
                acc[mi][ni] = __builtin_amdgcn_mfma_f32_16x16x32_bf16(
                    aF[mi], bF[ni], acc[mi][ni], 0, 0, 0);
        __syncthreads();
    }

    if (mode == 0) {
#pragma unroll
        for (int ni = 0; ni < 4; ni++) {
            int n = bn + wc * 64 + ni * 16 + l15;       // 0..3071
            int which = n >> 10;                         // 0=q 1=k 2=v
            int c = n & 1023;
            int nh = c >> 6, d = c & 63;
            const float* bias_p = (which == 0) ? bq : (which == 1) ? bk : bv;
            float bias = bias_p[c];
            float scl = (which == 0) ? 0.125f : 1.0f;
#pragma unroll
            for (int mi = 0; mi < 4; mi++) {
#pragma unroll
                for (int r = 0; r < 4; r++) {
                    int m = bm + wr * 64 + mi * 16 + g * 4 + r;  // token
                    int s = m >> 1, b = m & 1;
                    int head = b * NHEAD + nh;
                    bf16 val = (bf16)((acc[mi][ni][r] + bias) * scl);
                    if (which == 2)
                        vT[((size_t)(head * HDIM + d)) * S_LEN + s] = val;
                    else {
                        bf16* dst = (which == 0) ? qh : kh;
                        dst[((size_t)(head * S_LEN + s)) * HDIM + d] = val;
                    }
                }
            }
        }
    } else {
#pragma unroll
        for (int ni = 0; ni < 4; ni++) {
            int n = bn + wc * 64 + ni * 16 + l15;
            float bias = bo[n];
#pragma unroll
            for (int mi = 0; mi < 4; mi++) {
#pragma unroll
                for (int r = 0; r < 4; r++) {
                    int m = bm + wr * 64 + mi * 16 + g * 4 + r;
                    outp[(size_t)m * HID + n] = acc[mi][ni][r] + bias;
                }
            }
        }
    }
}

// ---------------- flash attention, swapped-QK + LDS mask DMA ----------------
// grid 1024 blocks; block = 4 waves: wave = (b, stsub). 32 q-rows/block, 64 keys/iter.
// Mask tile [32 q][64 k] fp32 DMA'd to LDS (XOR-rotated rows), double-buffered,
// issued 1 iter ahead; per-iter __syncthreads drains the DMA.
// Swapped QK^T (A=K, B=Q): lane (g,l15) holds score(q=l15, k=16c+4g+r) -> mask is
// a contiguous float4 per lane; softmax reduce = local 16 + xor16 + xor32.
__global__ __launch_bounds__(256, 4) void attn(
    const bf16* __restrict__ q, const bf16* __restrict__ k, const bf16* __restrict__ vT,
    const float* __restrict__ amask,   // [16][2048][2048]
    const float* __restrict__ kmask,   // [32][2048]
    bf16* __restrict__ ctx)            // [4096][1024]
{
    __shared__ __align__(16) float MB[2][32 * 64];   // mask dbuf, rotated rows
    __shared__ __align__(16) bf16 P[4][16][72];      // per-wave P tile (stride 144B)
    const int tid = threadIdx.x, lane = tid & 63, wv = tid >> 6;
    const int g = lane >> 4, l15 = lane & 15;
    const int b = wv >> 1, stsub = wv & 1;

    // XCD swizzle: virtual id groups 2 heads per XCD -> K/V/vT L2-resident.
    const int hw = blockIdx.y * 64 + blockIdx.x;     // grid (64, 16)
    const int vid = (hw & 7) * 128 + (hw >> 3);
    const int nh = vid >> 6;
    const int st0 = (vid & 63) * 32;                 // block q-base
    const int st0s = st0 + stsub * 16;               // wave q-base
    const int n = b * NHEAD + nh;

    // Q fragments (B-operand): B[kd=g*8+e][col=q=l15]
    const bf16* qrow = q + ((size_t)(n * S_LEN + st0s + l15)) * HDIM;
    bf16x8 bQ0 = *(const bf16x8*)(qrow + g * 8);
    bf16x8 bQ1 = *(const bf16x8*)(qrow + 32 + g * 8);

    // DMA source addresses (tt0-independent parts). Thread stages 16B; 2 instr/wave.
    // dest (linear): row_rel = wv*8 + j*4 + (lane>>4), col' = 4*(lane&15)
    // logical col = (col' - 4*row_rel) & 63   (XOR-rotation, inverse applied on src)
    const int row0 = wv * 8 + (lane >> 4);
    const int row1 = row0 + 4;
    const float* src0 = amask + ((size_t)nh * S_LEN + st0 + row0) * S_LEN
                        + ((4 * (lane & 15) - 4 * row0) & 63);
    const float* src1 = amask + ((size_t)nh * S_LEN + st0 + row1) * S_LEN
                        + ((4 * (lane & 15) - 4 * row1) & 63);
    float* dst0[2] = { &MB[0][(wv * 8) * 64],     &MB[1][(wv * 8) * 64] };
    float* dst1[2] = { &MB[0][(wv * 8 + 4) * 64], &MB[1][(wv * 8 + 4) * 64] };

    f32x4 zero4 = {0.f, 0.f, 0.f, 0.f};
    f32x4 O[4];
#pragma unroll
    for (int t = 0; t < 4; t++) O[t] = zero4;
    float mrow = -1e30f, lrow = 0.f;                 // per-lane: q = l15

    // A-operand K base: A[row=key=l15][kd=g*8+e]
    const bf16* kbase = k + ((size_t)n * S_LEN + l15) * HDIM + g * 8;
    // PV B-operand base: B[k=g*8+e][col=d=l15(+16dt)] from vT[dim][seq]
    const bf16* vbase = vT + ((size_t)n * HDIM + l15) * S_LEN + g * 8;
    const float* kmb = kmask + (size_t)n * S_LEN + 4 * g;
    const int rr = stsub * 16 + l15;                 // mask row this lane reads

    // prologue: stage iter-0 mask tile
    gload16(src0, dst0[0]);
    gload16(src1, dst1[0]);
    __syncthreads();

    for (int it = 0; it < 32; ++it) {
        const int tt0 = it * 64;
        const int cur = it & 1;
        // DMA next tile first (longest-latency stream, flies across the iter)
        if (it < 31) {
            gload16(src0 + tt0 + 64, dst0[cur ^ 1]);
            gload16(src1 + tt0 + 64, dst1[cur ^ 1]);
        }

        // ---- QK^T (swapped): sc[c][r] = score(q=l15, k=tt0+16c+4g+r) ----
        f32x4 sc[4];
#pragma unroll
        for (int c = 0; c < 4; c++) {
            const bf16* kp = kbase + (size_t)(tt0 + 16 * c) * HDIM;
            bf16x8 aK0 = *(const bf16x8*)kp;
            bf16x8 aK1 = *(const bf16x8*)(kp + 32);
            f32x4 s = zero4;
            s = __builtin_amdgcn_mfma_f32_16x16x32_bf16(aK0, bQ0, s, 0, 0, 0);
            s = __builtin_amdgcn_mfma_f32_16x16x32_bf16(aK1, bQ1, s, 0, 0, 0);
            sc[c] = s;
        }

        // ---- masks: LDS float4 (rotated) + global kmask float4 ----
#pragma unroll
        for (int c = 0; c < 4; c++) {
            f32x4 mk = *(const f32x4*)&MB[cur][rr * 64 + ((16 * c + 4 * g + 4 * rr) & 63)];
            f32x4 km = *(const f32x4*)(kmb + tt0 + 16 * c);
            sc[c] += mk + km;
        }

        // ---- online softmax (per-lane row q=l15) ----
        float cm = fmaxf(fmaxf(fmaxf(sc[0][0], sc[0][1]), fmaxf(sc[0][2], sc[0][3])),
                         fmaxf(fmaxf(sc[1][0], sc[1][1]), fmaxf(sc[1][2], sc[1][3])));
        cm = fmaxf(cm, fmaxf(fmaxf(fmaxf(sc[2][0], sc[2][1]), fmaxf(sc[2][2], sc[2][3])),
                             fmaxf(fmaxf(sc[3][0], sc[3][1]), fmaxf(sc[3][2], sc[3][3]))));
        cm = fmaxf(cm, __shfl_xor(cm, 16, 64));
        cm = fmaxf(cm, __shfl_xor(cm, 32, 64));
        if (!__all(cm - mrow <= 8.0f)) {             // defer-max
            float mn = fmaxf(mrow, cm);
            float f = __expf(mrow - mn);
            mrow = mn;
            lrow *= f;
#pragma unroll
            for (int r = 0; r < 4; r++) {
                float fb = __shfl(f, 4 * g + r, 64); // factor for q = 4g+r (O layout)
#pragma unroll
                for (int dt = 0; dt < 4; dt++) O[dt][r] *= fb;
            }
        }
        float rs = 0.f;
#pragma unroll
        for (int c = 0; c < 4; c++)
#pragma unroll
            for (int r = 0; r < 4; r++) {
                float p = __expf(sc[c][r] - mrow);
                sc[c][r] = p;
                rs += p;
            }
        rs += __shfl_xor(rs, 16, 64);
        rs += __shfl_xor(rs, 32, 64);
        lrow += rs;

        // ---- P -> LDS (per-wave): row q=l15, k-contig bf16x4 per c ----
#pragma unroll
        for (int c = 0; c < 4; c++) {
            bf16x4 pk;
            pk[0] = (bf16)sc[c][0]; pk[1] = (bf16)sc[c][1];
            pk[2] = (bf16)sc[c][2]; pk[3] = (bf16)sc[c][3];
            *(bf16x4*)&P[wv][l15][16 * c + 4 * g] = pk;
        }
        asm volatile("s_waitcnt lgkmcnt(0)" ::: "memory");
        __builtin_amdgcn_sched_barrier(0);
        bf16x8 aP0 = *(const bf16x8*)&P[wv][l15][g * 8];        // k 0..31
        bf16x8 aP1 = *(const bf16x8*)&P[wv][l15][32 + g * 8];   // k 32..63

        // ---- PV: O[q][d] += P[q][k] V[k][d] ----
#pragma unroll
        for (int dt = 0; dt < 4; dt++) {
            const bf16* vp = vbase + (size_t)(dt * 16) * S_LEN + tt0;
            bf16x8 bV0 = *(const bf16x8*)vp;
            bf16x8 bV1 = *(const bf16x8*)(vp + 32);
            O[dt] = __builtin_amdgcn_mfma_f32_16x16x32_bf16(aP0, bV0, O[dt], 0, 0, 0);
            O[dt] = __builtin_amdgcn_mfma_f32_16x16x32_bf16(aP1, bV1, O[dt], 0, 0, 0);
        }

        __syncthreads();   // drains DMA for next tile; all waves aligned
    }

    // ---- epilogue: O[dt][r] is (q=st0s+4g+r, d=nh*64+dt*16+l15); l lives at q=l15 ----
#pragma unroll
    for (int r = 0; r < 4; r++) {
        float lq = __shfl(lrow, 4 * g + r, 64);
        float inv = 1.0f / lq;
        int s = st0s + 4 * g + r;
        int token = s * BATCH + b;
#pragma unroll
        for (int dt = 0; dt < 4; dt++) {
            int h = nh * HDIM + dt * 16 + l15;
            ctx[(size_t)token * HID + h] = (bf16)(O[dt][r] * inv);
        }
    }
}

extern "C" void kernel_launch(void* const* d_in, const int* in_sizes, int n_in,
                              void* d_out, int out_size, void* d_ws, size_t ws_size,
                              hipStream_t stream) {
    const float* hidden = (const float*)d_in[0];
    const float* amask  = (const float*)d_in[1];
    const float* kmask  = (const float*)d_in[2];
    const float* Wq = (const float*)d_in[3];
    const float* bq = (const float*)d_in[4];
    const float* Wk = (const float*)d_in[5];
    const float* bk = (const float*)d_in[6];
    const float* Wv = (const float*)d_in[7];
    const float* bv = (const float*)d_in[8];
    const float* Wo = (const float*)d_in[9];
    const float* bo = (const float*)d_in[10];
    float* out = (float*)d_out;

    char* ws = (char*)d_ws;
    bf16* Xb   = (bf16*)(ws);                       // 8 MB  [4096][1024]
    bf16* Wcat = (bf16*)(ws + (8u  << 20));         // 6 MB  [3072][1024]
    bf16* Wob  = (bf16*)(ws + (14u << 20));         // 2 MB  [1024][1024]
    bf16* qh   = (bf16*)(ws + (16u << 20));         // 8 MB  [32][2048][64]
    bf16* kh   = (bf16*)(ws + (24u << 20));         // 8 MB
    bf16* vT   = (bf16*)(ws + (40u << 20));         // 8 MB  [32][64][2048]
    bf16* ctx  = (bf16*)(ws + (48u << 20));         // 8 MB  [4096][1024]

    cvt_f32_bf16<<<2048, 256, 0, stream>>>(hidden, Xb, NTOK * HID);
    cvt_f32_bf16<<<512, 256, 0, stream>>>(Wq, Wcat,              HID * HID);
    cvt_f32_bf16<<<512, 256, 0, stream>>>(Wk, Wcat + HID * HID,  HID * HID);
    cvt_f32_bf16<<<512, 256, 0, stream>>>(Wv, Wcat + 2 * HID * HID, HID * HID);
    cvt_f32_bf16<<<512, 256, 0, stream>>>(Wo, Wob, HID * HID);

    gemm_bt<<<dim3(24, 32), 256, 0, stream>>>(Xb, Wcat, NTOK, 3 * HID, HID, 0,
                                              bq, bk, bv, bo, qh, kh, vT, nullptr);
    attn<<<dim3(64, 16), 256, 0, stream>>>(qh, kh, vT, amask, kmask, ctx);
    gemm_bt<<<dim3(8, 32), 256, 0, stream>>>(ctx, Wob, NTOK, HID, HID, 1,
                                             bq, bk, bv, bo, qh, kh, vT, out);
}

// Round 5
// 374.443 us; speedup vs baseline: 1.0002x; 1.0002x over previous
//
#include <hip/hip_runtime.h>
#include <hip/hip_bf16.h>
#include <math.h>

#define S_LEN 2048
#define BATCH 2
#define HID 1024
#define NHEAD 16
#define HDIM 64
#define NTOK (S_LEN*BATCH)   // 4096

typedef __bf16 bf16;
typedef __bf16 bf16x4 __attribute__((ext_vector_type(4)));
typedef __bf16 bf16x8 __attribute__((ext_vector_type(8)));
typedef float f32x4 __attribute__((ext_vector_type(4)));

typedef const __attribute__((address_space(1))) unsigned int* gptr_t;
typedef __attribute__((address_space(3))) unsigned int* lptr_t;

__device__ __forceinline__ void gload16(const void* g, void* l) {
    __builtin_amdgcn_global_load_lds((gptr_t)g, (lptr_t)l, 16, 0, 0);
}

// ---------------- fp32 -> bf16 convert (8 elems/thread) ----------------
__global__ void cvt_f32_bf16(const float* __restrict__ src, bf16* __restrict__ dst, int n) {
    int i = (blockIdx.x * blockDim.x + threadIdx.x) * 8;
    if (i >= n) return;
    const float4* s = (const float4*)(src + i);
    float4 a = s[0], b = s[1];
    bf16x8 o;
    o[0] = (bf16)a.x; o[1] = (bf16)a.y; o[2] = (bf16)a.z; o[3] = (bf16)a.w;
    o[4] = (bf16)b.x; o[5] = (bf16)b.y; o[6] = (bf16)b.z; o[7] = (bf16)b.w;
    *(bf16x8*)(dst + i) = o;
}

// ---------------- GEMM: C[M][N] = A[M][K] * B[N][K]^T ----------------
// mode 0: QKV epilogue (N=3072): q/k -> head layout [32][2048][64]; v -> vT [32][64][2048]
// mode 1: OUT epilogue (N=1024): fp32 token-major + bias
#define BM 128
#define BN 128
#define BK 32

__global__ __launch_bounds__(256) void gemm_bt(
    const bf16* __restrict__ A, const bf16* __restrict__ B,
    int M, int N, int K, int mode,
    const float* __restrict__ bq, const float* __restrict__ bk,
    const float* __restrict__ bv, const float* __restrict__ bo,
    bf16* __restrict__ qh, bf16* __restrict__ kh, bf16* __restrict__ vT,
    float* __restrict__ outp)
{
    __shared__ __align__(16) bf16 As[BM * BK];
    __shared__ __align__(16) bf16 Bs[BN * BK];
    const int tid = threadIdx.x;
    const int lane = tid & 63, wv = tid >> 6;
    const int g = lane >> 4, l15 = lane & 15;
    const int wr = wv >> 1, wc = wv & 1;
    const int bm = blockIdx.y * BM, bn = blockIdx.x * BN;

    f32x4 zero4 = {0.f, 0.f, 0.f, 0.f};
    f32x4 acc[4][4];
#pragma unroll
    for (int mi = 0; mi < 4; mi++)
#pragma unroll
        for (int ni = 0; ni < 4; ni++) acc[mi][ni] = zero4;

    const int r0 = wv * 32 + (lane >> 2);
    const int c0 = (lane & 3) * 8;
    const bf16* Ag0 = A + (size_t)(bm + r0) * K + c0;
    const bf16* Ag1 = Ag0 + (size_t)16 * K;
    const bf16* Bg0 = B + (size_t)(bn + r0) * K + c0;
    const bf16* Bg1 = Bg0 + (size_t)16 * K;
    bf16* AsW = &As[(wv * 32) * BK];
    bf16* BsW = &Bs[(wv * 32) * BK];

    for (int k0 = 0; k0 < K; k0 += BK) {
        gload16(Ag0 + k0, AsW);
        gload16(Ag1 + k0, AsW + 16 * BK);
        gload16(Bg0 + k0, BsW);
        gload16(Bg1 + k0, BsW + 16 * BK);
        __syncthreads();

        bf16x8 aF[4], bF[4];
#pragma unroll
        for (int mi = 0; mi < 4; mi++)
            aF[mi] = *(const bf16x8*)&As[(wr * 64 + mi * 16 + l15) * BK + g * 8];
#pragma unroll
        for (int ni = 0; ni < 4; ni++)
            bF[ni] = *(const bf16x8*)&Bs[(wc * 64 + ni * 16 + l15) * BK + g * 8];
#pragma unroll
        for (int mi = 0; mi < 4; mi++)
#pragma unroll
            for (int ni = 0; ni < 4; ni++)
                acc[mi][ni] = __builtin_amdgcn_mfma_f32_16x16x32_bf16(
                    aF[mi], bF[ni], acc[mi][ni], 0, 0, 0);
        __syncthreads();
    }

    if (mode == 0) {
#pragma unroll
        for (int ni = 0; ni < 4; ni++) {
            int n = bn + wc * 64 + ni * 16 + l15;       // 0..3071
            int which = n >> 10;                         // 0=q 1=k 2=v
            int c = n & 1023;
            int nh = c >> 6, d = c & 63;
            const float* bias_p = (which == 0) ? bq : (which == 1) ? bk : bv;
            float bias = bias_p[c];
            float scl = (which == 0) ? 0.125f : 1.0f;
#pragma unroll
            for (int mi = 0; mi < 4; mi++) {
#pragma unroll
                for (int r = 0; r < 4; r++) {
                    int m = bm + wr * 64 + mi * 16 + g * 4 + r;  // token
                    int s = m >> 1, b = m & 1;
                    int head = b * NHEAD + nh;
                    bf16 val = (bf16)((acc[mi][ni][r] + bias) * scl);
                    if (which == 2)
                        vT[((size_t)(head * HDIM + d)) * S_LEN + s] = val;
                    else {
                        bf16* dst = (which == 0) ? qh : kh;
                        dst[((size_t)(head * S_LEN + s)) * HDIM + d] = val;
                    }
                }
            }
        }
    } else {
#pragma unroll
        for (int ni = 0; ni < 4; ni++) {
            int n = bn + wc * 64 + ni * 16 + l15;
            float bias = bo[n];
#pragma unroll
            for (int mi = 0; mi < 4; mi++) {
#pragma unroll
                for (int r = 0; r < 4; r++) {
                    int m = bm + wr * 64 + mi * 16 + g * 4 + r;
                    outp[(size_t)m * HID + n] = acc[mi][ni][r] + bias;
                }
            }
        }
    }
}

// ---------------- flash attention, swapped-QK + LDS mask DMA ----------------
// grid 1024 blocks; block = 4 waves: wave = (b, stsub). 32 q-rows/block, 64 keys/iter.
// Mask tile [32 q][64 k] fp32 DMA'd to LDS (XOR-rotated rows), double-buffered,
// issued 1 iter ahead; per-iter __syncthreads drains the DMA.
// Swapped QK^T (A=K, B=Q): lane (g,l15) holds score(q=l15, k=16c+4g+r) -> mask is
// a contiguous float4 per lane; softmax reduce = local 16 + xor16 + xor32.
__global__ __launch_bounds__(256, 4) void attn(
    const bf16* __restrict__ q, const bf16* __restrict__ k, const bf16* __restrict__ vT,
    const float* __restrict__ amask,   // [16][2048][2048]
    const float* __restrict__ kmask,   // [32][2048]
    bf16* __restrict__ ctx)            // [4096][1024]
{
    __shared__ __align__(16) float MB[2][32 * 64];   // mask dbuf, rotated rows
    __shared__ __align__(16) bf16 P[4][16][72];      // per-wave P tile (stride 144B)
    const int tid = threadIdx.x, lane = tid & 63, wv = tid >> 6;
    const int g = lane >> 4, l15 = lane & 15;
    const int b = wv >> 1, stsub = wv & 1;

    // XCD swizzle: virtual id groups 2 heads per XCD -> K/V/vT L2-resident.
    const int hw = blockIdx.y * 64 + blockIdx.x;     // grid (64, 16)
    const int vid = (hw & 7) * 128 + (hw >> 3);
    const int nh = vid >> 6;
    const int st0 = (vid & 63) * 32;                 // block q-base
    const int st0s = st0 + stsub * 16;               // wave q-base
    const int n = b * NHEAD + nh;

    // Q fragments (B-operand): B[kd=g*8+e][col=q=l15]
    const bf16* qrow = q + ((size_t)(n * S_LEN + st0s + l15)) * HDIM;
    bf16x8 bQ0 = *(const bf16x8*)(qrow + g * 8);
    bf16x8 bQ1 = *(const bf16x8*)(qrow + 32 + g * 8);

    // DMA source addresses (tt0-independent parts). Thread stages 16B; 2 instr/wave.
    // dest (linear): row_rel = wv*8 + j*4 + (lane>>4), col' = 4*(lane&15)
    // logical col = (col' - 4*row_rel) & 63   (XOR-rotation, inverse applied on src)
    const int row0 = wv * 8 + (lane >> 4);
    const int row1 = row0 + 4;
    const float* src0 = amask + ((size_t)nh * S_LEN + st0 + row0) * S_LEN
                        + ((4 * (lane & 15) - 4 * row0) & 63);
    const float* src1 = amask + ((size_t)nh * S_LEN + st0 + row1) * S_LEN
                        + ((4 * (lane & 15) - 4 * row1) & 63);
    float* dst0[2] = { &MB[0][(wv * 8) * 64],     &MB[1][(wv * 8) * 64] };
    float* dst1[2] = { &MB[0][(wv * 8 + 4) * 64], &MB[1][(wv * 8 + 4) * 64] };

    f32x4 zero4 = {0.f, 0.f, 0.f, 0.f};
    f32x4 O[4];
#pragma unroll
    for (int t = 0; t < 4; t++) O[t] = zero4;
    float mrow = -1e30f, lrow = 0.f;                 // per-lane: q = l15

    // A-operand K base: A[row=key=l15][kd=g*8+e]
    const bf16* kbase = k + ((size_t)n * S_LEN + l15) * HDIM + g * 8;
    // PV B-operand base: B[k=g*8+e][col=d=l15(+16dt)] from vT[dim][seq]
    const bf16* vbase = vT + ((size_t)n * HDIM + l15) * S_LEN + g * 8;
    const float* kmb = kmask + (size_t)n * S_LEN + 4 * g;
    const int rr = stsub * 16 + l15;                 // mask row this lane reads

    // prologue: stage iter-0 mask tile
    gload16(src0, dst0[0]);
    gload16(src1, dst1[0]);
    __syncthreads();

    for (int it = 0; it < 32; ++it) {
        const int tt0 = it * 64;
        const int cur = it & 1;
        // DMA next tile first (longest-latency stream, flies across the iter)
        if (it < 31) {
            gload16(src0 + tt0 + 64, dst0[cur ^ 1]);
            gload16(src1 + tt0 + 64, dst1[cur ^ 1]);
        }

        // ---- QK^T (swapped): sc[c][r] = score(q=l15, k=tt0+16c+4g+r) ----
        f32x4 sc[4];
#pragma unroll
        for (int c = 0; c < 4; c++) {
            const bf16* kp = kbase + (size_t)(tt0 + 16 * c) * HDIM;
            bf16x8 aK0 = *(const bf16x8*)kp;
            bf16x8 aK1 = *(const bf16x8*)(kp + 32);
            f32x4 s = zero4;
            s = __builtin_amdgcn_mfma_f32_16x16x32_bf16(aK0, bQ0, s, 0, 0, 0);
            s = __builtin_amdgcn_mfma_f32_16x16x32_bf16(aK1, bQ1, s, 0, 0, 0);
            sc[c] = s;
        }

        // ---- masks: LDS float4 (rotated) + global kmask float4 ----
#pragma unroll
        for (int c = 0; c < 4; c++) {
            f32x4 mk = *(const f32x4*)&MB[cur][rr * 64 + ((16 * c + 4 * g + 4 * rr) & 63)];
            f32x4 km = *(const f32x4*)(kmb + tt0 + 16 * c);
            sc[c] += mk + km;
        }

        // ---- online softmax (per-lane row q=l15) ----
        float cm = fmaxf(fmaxf(fmaxf(sc[0][0], sc[0][1]), fmaxf(sc[0][2], sc[0][3])),
                         fmaxf(fmaxf(sc[1][0], sc[1][1]), fmaxf(sc[1][2], sc[1][3])));
        cm = fmaxf(cm, fmaxf(fmaxf(fmaxf(sc[2][0], sc[2][1]), fmaxf(sc[2][2], sc[2][3])),
                             fmaxf(fmaxf(sc[3][0], sc[3][1]), fmaxf(sc[3][2], sc[3][3]))));
        cm = fmaxf(cm, __shfl_xor(cm, 16, 64));
        cm = fmaxf(cm, __shfl_xor(cm, 32, 64));
        if (!__all(cm - mrow <= 8.0f)) {             // defer-max
            float mn = fmaxf(mrow, cm);
            float f = __expf(mrow - mn);
            mrow = mn;
            lrow *= f;
#pragma unroll
            for (int r = 0; r < 4; r++) {
                float fb = __shfl(f, 4 * g + r, 64); // factor for q = 4g+r (O layout)
#pragma unroll
                for (int dt = 0; dt < 4; dt++) O[dt][r] *= fb;
            }
        }
        float rs = 0.f;
#pragma unroll
        for (int c = 0; c < 4; c++)
#pragma unroll
            for (int r = 0; r < 4; r++) {
                float p = __expf(sc[c][r] - mrow);
                sc[c][r] = p;
                rs += p;
            }
        rs += __shfl_xor(rs, 16, 64);
        rs += __shfl_xor(rs, 32, 64);
        lrow += rs;

        // ---- P -> LDS (per-wave): row q=l15, k-contig bf16x4 per c ----
#pragma unroll
        for (int c = 0; c < 4; c++) {
            bf16x4 pk;
            pk[0] = (bf16)sc[c][0]; pk[1] = (bf16)sc[c][1];
            pk[2] = (bf16)sc[c][2]; pk[3] = (bf16)sc[c][3];
            *(bf16x4*)&P[wv][l15][16 * c + 4 * g] = pk;
        }
        asm volatile("s_waitcnt lgkmcnt(0)" ::: "memory");
        __builtin_amdgcn_sched_barrier(0);
        bf16x8 aP0 = *(const bf16x8*)&P[wv][l15][g * 8];        // k 0..31
        bf16x8 aP1 = *(const bf16x8*)&P[wv][l15][32 + g * 8];   // k 32..63

        // ---- PV: O[q][d] += P[q][k] V[k][d] ----
#pragma unroll
        for (int dt = 0; dt < 4; dt++) {
            const bf16* vp = vbase + (size_t)(dt * 16) * S_LEN + tt0;
            bf16x8 bV0 = *(const bf16x8*)vp;
            bf16x8 bV1 = *(const bf16x8*)(vp + 32);
            O[dt] = __builtin_amdgcn_mfma_f32_16x16x32_bf16(aP0, bV0, O[dt], 0, 0, 0);
            O[dt] = __builtin_amdgcn_mfma_f32_16x16x32_bf16(aP1, bV1, O[dt], 0, 0, 0);
        }

        __syncthreads();   // drains DMA for next tile; all waves aligned
    }

    // ---- epilogue: O[dt][r] is (q=st0s+4g+r, d=nh*64+dt*16+l15); l lives at q=l15 ----
#pragma unroll
    for (int r = 0; r < 4; r++) {
        float lq = __shfl(lrow, 4 * g + r, 64);
        float inv = 1.0f / lq;
        int s = st0s + 4 * g + r;
        int token = s * BATCH + b;
#pragma unroll
        for (int dt = 0; dt < 4; dt++) {
            int h = nh * HDIM + dt * 16 + l15;
            ctx[(size_t)token * HID + h] = (bf16)(O[dt][r] * inv);
        }
    }
}

extern "C" void kernel_launch(void* const* d_in, const int* in_sizes, int n_in,
                              void* d_out, int out_size, void* d_ws, size_t ws_size,
                              hipStream_t stream) {
    const float* hidden = (const float*)d_in[0];
    const float* amask  = (const float*)d_in[1];
    const float* kmask  = (const float*)d_in[2];
    const float* Wq = (const float*)d_in[3];
    const float* bq = (const float*)d_in[4];
    const float* Wk = (const float*)d_in[5];
    const float* bk = (const float*)d_in[6];
    const float* Wv = (const float*)d_in[7];
    const float* bv = (const float*)d_in[8];
    const float* Wo = (const float*)d_in[9];
    const float* bo = (const float*)d_in[10];
    float* out = (float*)d_out;

    char* ws = (char*)d_ws;
    bf16* Xb   = (bf16*)(ws);                       // 8 MB  [4096][1024]
    bf16* Wcat = (bf16*)(ws + (8u  << 20));         // 6 MB  [3072][1024]
    bf16* Wob  = (bf16*)(ws + (14u << 20));         // 2 MB  [1024][1024]
    bf16* qh   = (bf16*)(ws + (16u << 20));         // 8 MB  [32][2048][64]
    bf16* kh   = (bf16*)(ws + (24u << 20));         // 8 MB
    bf16* vT   = (bf16*)(ws + (40u << 20));         // 8 MB  [32][64][2048]
    bf16* ctx  = (bf16*)(ws + (48u << 20));         // 8 MB  [4096][1024]

    cvt_f32_bf16<<<2048, 256, 0, stream>>>(hidden, Xb, NTOK * HID);
    cvt_f32_bf16<<<512, 256, 0, stream>>>(Wq, Wcat,              HID * HID);
    cvt_f32_bf16<<<512, 256, 0, stream>>>(Wk, Wcat + HID * HID,  HID * HID);
    cvt_f32_bf16<<<512, 256, 0, stream>>>(Wv, Wcat + 2 * HID * HID, HID * HID);
    cvt_f32_bf16<<<512, 256, 0, stream>>>(Wo, Wob, HID * HID);

    gemm_bt<<<dim3(24, 32), 256, 0, stream>>>(Xb, Wcat, NTOK, 3 * HID, HID, 0,
                                              bq, bk, bv, bo, qh, kh, vT, nullptr);
    attn<<<dim3(64, 16), 256, 0, stream>>>(qh, kh, vT, amask, kmask, ctx);
    gemm_bt<<<dim3(8, 32), 256, 0, stream>>>(ctx, Wob, NTOK, HID, HID, 1,
                                             bq, bk, bv, bo, qh, kh, vT, out);
}